// Round 13
// baseline (287.205 us; speedup 1.0000x reference)
//
#include <hip/hip_runtime.h>
#include <stdint.h>

#define BATCH 4
#define HH 128
#define WW 128
#define CIN 256
#define CO 512
#define HP 130
#define NPIX (BATCH*HH*WW)          // 65536
#define LOGITS_N (NPIX*6)           // 393216
#define DELTA_BASE (2*LOGITS_N)     // 786432

typedef short bf16x8 __attribute__((ext_vector_type(8)));
typedef unsigned short u16x8 __attribute__((ext_vector_type(8)));
typedef float f32x4 __attribute__((ext_vector_type(4)));
typedef unsigned int u32;

__device__ __forceinline__ unsigned short f2bf(float f) {
    union { float f; unsigned int u; } v; v.f = f;
    return (unsigned short)((v.u + 0x7FFFu + ((v.u >> 16) & 1u)) >> 16);
}

__device__ __forceinline__ void gload16(const unsigned short* g, char* l) {
    __builtin_amdgcn_global_load_lds(
        (const __attribute__((address_space(1))) u32*)g,
        (__attribute__((address_space(3))) u32*)l, 16, 0, 0);
}

// ---- pass 1a: fp32 input -> bf16 with 1-pixel zero halo: [B][130][130][256]
__global__ __launch_bounds__(256) void k_pad_convert(const float* __restrict__ in,
                                                     unsigned short* __restrict__ out) {
    size_t q = (size_t)blockIdx.x*256 + threadIdx.x;     // quad index (4 channels)
    if (q >= (size_t)BATCH*HP*HP*64) return;
    int c4 = ((int)q & 63) * 4;
    int pix = (int)(q >> 6);
    int xx = pix % HP; int t = pix / HP; int yy = t % HP; int b = t / HP;
    ushort4 r = {0, 0, 0, 0};
    if (yy >= 1 && yy <= HH && xx >= 1 && xx <= WW) {
        const float4 v = *(const float4*)(in + (((size_t)(b*HH) + (yy-1))*WW + (xx-1))*CIN + c4);
        r.x = f2bf(v.x); r.y = f2bf(v.y); r.z = f2bf(v.z); r.w = f2bf(v.w);
    }
    *(ushort4*)(out + (size_t)pix*CIN + c4) = r;
}

// ---- pass 1b: w_shared [9][256][512] fp32 -> wT [9][512][256] bf16
__global__ __launch_bounds__(256) void k_wt_convert(const float* __restrict__ w,
                                                    unsigned short* __restrict__ wt) {
    int n = blockIdx.x % CO; int tap = blockIdx.x / CO;
    int c = threadIdx.x;
    wt[((size_t)tap*CO + n)*CIN + c] = f2bf(w[((size_t)tap*CIN + c)*CO + n]);
}

// ==== main: 256x256 tile, 16x16x32 MFMA; A via LDS (triple buf, depth-2);
// ==== B DIRECT global->VGPR from L2 (no LDS round-trip), loaded per step.
// LDS 96 KiB (A only); kk-split MFMA: 32 MFMA with breg0 then 32 with breg1.
__global__ __launch_bounds__(512, 2) void k_main8(
    const unsigned short* __restrict__ in_p,   // bf16 padded input
    const unsigned short* __restrict__ wt,     // bf16 wT [9][512][256]
    const float* __restrict__ b_sh,
    const float* __restrict__ w_cls,
    const float* __restrict__ w_dlt,
    float* __restrict__ part)                  // [2][NPIX][18]
{
    extern __shared__ char LDS[];

    const int tid  = threadIdx.x;
    const int lane = tid & 63, wave = tid >> 6;
    const int l15  = lane & 15, l4 = lane >> 4;
    const int wm   = wave >> 2, wn = wave & 3;

    // XCD-contiguous bijective swizzle (512 % 8 == 0)
    const int bid   = ((blockIdx.x & 7) << 6) + (blockIdx.x >> 3);
    const int ntile = bid & 1, mtile = bid >> 1;
    const int n0 = ntile << 8;
    const int b  = mtile >> 6;
    const int y0 = (mtile & 63) * 2;           // tile covers image rows y0, y0+1

    // per-thread A staging offset (inverse XOR on source; linear LDS dest)
    const int rl0 = tid >> 3, pc0 = tid & 7;
    const int kc0 = pc0 ^ (rl0 & 7);
    const int off = rl0*256 + kc0*8;           // elements
    const int t16 = tid*16;                    // LDS dest byte offset

    // A fragment LDS byte offsets (XOR-swizzled reads), relative to each A buffer
    int base_a[2];
    #pragma unroll
    for (int kk = 0; kk < 2; kk++) {
        int swz = ((kk*32 + l4*8)*2) ^ ((l15 & 7) << 4);
        base_a[kk] = (wm*128 + l15)*128 + swz;
    }

    // B per-lane base: row = n0 + wn*64 + (ni*16) + l15, col base = l4*8
    const unsigned short* gBl = wt + (size_t)(n0 + wn*64 + l15)*256 + l4*8;

    f32x4 acc[8][4];
    const f32x4 zz = {0.f, 0.f, 0.f, 0.f};
    #pragma unroll
    for (int mi = 0; mi < 8; mi++)
        #pragma unroll
        for (int ni = 0; ni < 4; ni++) acc[mi][ni] = zz;

    // ---- prologue: stage A(0) -> buf0, A(1) -> buf1
    {
        const unsigned short* gA0 = in_p + ((size_t)(b*HP + y0))*HP*256;       // tap0,kq0
        const unsigned short* gA1 = gA0 + 64;                                  // tap0,kq1
        gload16(gA0 + off,          LDS + t16);
        gload16(gA0 + 16384 + off,  LDS + 8192 + t16);
        gload16(gA0 + 33280 + off,  LDS + 16384 + t16);
        gload16(gA0 + 49664 + off,  LDS + 24576 + t16);
        __builtin_amdgcn_sched_barrier(0);
        gload16(gA1 + off,          LDS + 32768 + t16);
        gload16(gA1 + 16384 + off,  LDS + 40960 + t16);
        gload16(gA1 + 33280 + off,  LDS + 49152 + t16);
        gload16(gA1 + 49664 + off,  LDS + 57344 + t16);
    }
    asm volatile("s_waitcnt vmcnt(4)" ::: "memory");      // A(0) landed; A(1) may fly
    __builtin_amdgcn_sched_barrier(0);
    __builtin_amdgcn_s_barrier();
    __builtin_amdgcn_sched_barrier(0);

#define LOAD_Q(AQ, Q)                                                        \
    _Pragma("unroll")                                                        \
    for (int kk = 0; kk < 2; kk++) {                                         \
        AQ[0][kk] = *(const bf16x8*)(bufA + base_a[kk] + (2*(Q))*2048);      \
        AQ[1][kk] = *(const bf16x8*)(bufA + base_a[kk] + (2*(Q)+1)*2048);    \
    }

#define MFMA_K(Q, AQ, KK, BREG)                                              \
    __builtin_amdgcn_s_setprio(1);                                           \
    _Pragma("unroll")                                                        \
    for (int mm = 0; mm < 2; mm++)                                           \
        _Pragma("unroll")                                                    \
        for (int ni = 0; ni < 4; ni++)                                       \
            acc[2*(Q)+mm][ni] = __builtin_amdgcn_mfma_f32_16x16x32_bf16(     \
                AQ[mm][KK], BREG[ni], acc[2*(Q)+mm][ni], 0, 0, 0);           \
    __builtin_amdgcn_s_setprio(0);

    int ia = 0;                                 // A read buffer index (s % 3)
    for (int s = 0; s < 36; ++s) {
        // B(s) source offset (loaded THIS step, direct to VGPR)
        const int tap0 = s >> 2, kq0 = s & 3;
        const unsigned short* gB = gBl + (size_t)tap0*131072 + kq0*64;
        // A(s+2) staging source
        const int s2p = s + 2;
        const int tapA = s2p >> 2, kqA = s2p & 3;
        const int dyA = (tapA*11) >> 5, dxA = tapA - dyA*3;
        const unsigned short* gA = in_p + ((size_t)((b*HP + y0 + dyA)*HP + dxA))*256 + kqA*64;

        const char* bufA = LDS + (ia << 15);
        int iw = ia + 2; if (iw > 2) iw -= 3;
        char* Ad = LDS + (iw << 15);
        const bool moreA = (s < 34);

        // ---- issue B loads first (longest latency): breg0 = kk0, breg1 = kk1
        bf16x8 breg0[4], breg1[4];
        #pragma unroll
        for (int ni = 0; ni < 4; ni++) breg0[ni] = *(const bf16x8*)(gB + ni*4096);
        #pragma unroll
        for (int ni = 0; ni < 4; ni++) breg1[ni] = *(const bf16x8*)(gB + 32 + ni*4096);
        __builtin_amdgcn_sched_barrier(0);

        // ---- A quad reads (LDS) + A(s+2) staging, interleaved
        bf16x8 a0[2][2], a1[2][2], a2[2][2], a3[2][2];
        LOAD_Q(a0, 0)
        LOAD_Q(a1, 1)
        __builtin_amdgcn_sched_barrier(0);
        if (moreA) {
            gload16(gA + off,          Ad + t16);
            gload16(gA + 16384 + off,  Ad + 8192 + t16);
            gload16(gA + 33280 + off,  Ad + 16384 + t16);
            gload16(gA + 49664 + off,  Ad + 24576 + t16);
        }
        __builtin_amdgcn_sched_barrier(0);
        LOAD_Q(a2, 2)
        LOAD_Q(a3, 3)

        // breg0 landed: outstanding <= breg1(4) + Astage(4 if moreA)
        if (moreA) { asm volatile("s_waitcnt vmcnt(8)" ::: "memory"); }
        else       { asm volatile("s_waitcnt vmcnt(4)" ::: "memory"); }
        __builtin_amdgcn_sched_barrier(0);
        MFMA_K(0, a0, 0, breg0)
        MFMA_K(1, a1, 0, breg0)
        MFMA_K(2, a2, 0, breg0)
        MFMA_K(3, a3, 0, breg0)

        // breg1 landed (implies A(s+1), older, landed too): outstanding <= Astage(s+2)
        if (moreA) { asm volatile("s_waitcnt vmcnt(4)" ::: "memory"); }
        else       { asm volatile("s_waitcnt vmcnt(0)" ::: "memory"); }
        __builtin_amdgcn_sched_barrier(0);
        MFMA_K(0, a0, 1, breg1)
        MFMA_K(1, a1, 1, breg1)
        MFMA_K(2, a2, 1, breg1)
        MFMA_K(3, a3, 1, breg1)

        __builtin_amdgcn_sched_barrier(0);
        __builtin_amdgcn_s_barrier();
        __builtin_amdgcn_sched_barrier(0);

        ia = ia == 2 ? 0 : ia + 1;
    }
#undef LOAD_Q
#undef MFMA_K

    // ---- epilogue: bias+ReLU + 1x1-head partial reduction over this block's 256 channels
    float* shf = (float*)LDS;                  // [64 cols][260] = 66560 B
    float* sW  = (float*)(LDS + 66560);        // [256][20] = 20480 B (total 87040 <= 96K)
    for (int j = tid; j < 256*18; j += 512) {
        int c = j / 18, o = j - c*18;
        sW[c*20 + o] = (o < 6) ? w_cls[(size_t)(n0 + c)*6 + o]
                               : w_dlt[(size_t)(n0 + c)*12 + (o - 6)];
    }
    float bsh[4];
    #pragma unroll
    for (int ni = 0; ni < 4; ni++) bsh[ni] = b_sh[n0 + wn*64 + ni*16 + l15];

    float a18[18];
    #pragma unroll
    for (int o = 0; o < 18; o++) a18[o] = 0.f;
    const int rr = tid & 255, chalf = tid >> 8;
    __syncthreads();

    for (int p = 0; p < 4; ++p) {
        if (wn == p) {
            #pragma unroll
            for (int mi = 0; mi < 8; mi++)
                #pragma unroll
                for (int ni = 0; ni < 4; ni++) {
                    int colL = ni*16 + l15;
                    int row0 = wm*128 + mi*16 + l4*4;
                    f32x4 v = acc[mi][ni];
                    f32x4 sv;
                    #pragma unroll
                    for (int r = 0; r < 4; r++) sv[r] = fmaxf(v[r] + bsh[ni], 0.f);
                    *(f32x4*)(shf + colL*260 + row0) = sv;
                }
        }
        __syncthreads();
        #pragma unroll 4
        for (int i = 0; i < 32; i++) {
            int c = chalf*32 + i;
            float v = shf[c*260 + rr];
            const float* wrow = sW + (p*64 + c)*20;
            #pragma unroll
            for (int o = 0; o < 18; o++) a18[o] += v * wrow[o];
        }
        __syncthreads();
    }

    if (chalf == 1) {
        #pragma unroll
        for (int o = 0; o < 18; o++) shf[rr*18 + o] = a18[o];
    }
    __syncthreads();
    if (chalf == 0) {
        float* dst = part + ((size_t)ntile*NPIX + (size_t)mtile*256 + rr)*18;
        #pragma unroll
        for (int o = 0; o < 18; o++) dst[o] = a18[o] + shf[rr*18 + o];
    }
}

// ---- finalize (ws path): sum 2 partials, biases, softmax -> all outputs
__global__ __launch_bounds__(256) void k_finalize_ws(const float* __restrict__ part,
                                                     float* __restrict__ out,
                                                     const float* __restrict__ b_cls,
                                                     const float* __restrict__ b_dlt) {
    int pix = blockIdx.x*256 + threadIdx.x;
    if (pix >= NPIX) return;
    float s[18];
    #pragma unroll
    for (int o = 0; o < 18; o++)
        s[o] = part[(size_t)pix*18 + o] + part[((size_t)NPIX + pix)*18 + o];
    float* lo = out + (size_t)pix*6;
    float* pr = out + (size_t)LOGITS_N + (size_t)pix*6;
    float* dl = out + (size_t)DELTA_BASE + (size_t)pix*12;
    #pragma unroll
    for (int a = 0; a < 3; a++) {
        float l0 = s[a*2]   + b_cls[a*2];
        float l1 = s[a*2+1] + b_cls[a*2+1];
        lo[a*2] = l0; lo[a*2+1] = l1;
        float m = fmaxf(l0, l1);
        float e0 = __expf(l0 - m), e1 = __expf(l1 - m);
        float inv = 1.f / (e0 + e1);
        pr[a*2] = e0*inv; pr[a*2+1] = e1*inv;
    }
    #pragma unroll
    for (int o = 0; o < 12; o++) dl[o] = s[6 + o] + b_dlt[o];
}

// ======== fallback path (no workspace): round-2 proven kernel, atomics ========
__global__ __launch_bounds__(256) void k_main_fb(
    const float* __restrict__ in_f, const float* __restrict__ w_f,
    const float* __restrict__ b_sh, const float* __restrict__ w_cls,
    const float* __restrict__ w_dlt, float* __restrict__ out)
{
    __shared__ float smemf[11008];
    char* smem  = (char*)smemf;
    char* smemB = smem + 16384;
    const int tid = threadIdx.x;
    const int lane = tid & 63, wave = tid >> 6;
    const int l15 = lane & 15, l4 = lane >> 4;
    const int wr = wave >> 1, wc = wave & 1;
    int bid = ((blockIdx.x & 7) << 8) + (blockIdx.x >> 3);
    const int ntile = bid & 3, mtile = bid >> 2;
    const int n0 = ntile << 7;
    const int b = mtile >> 7, y = mtile & 127;
    int aoff[4][2], boff[4][2];
    #pragma unroll
    for (int mi = 0; mi < 4; mi++) {
        int rowA = wr*64 + mi*16 + l15;
        int rowB = wc*64 + mi*16 + l15;
        #pragma unroll
        for (int kk = 0; kk < 2; kk++) {
            int kb = (kk*32 + l4*8) * 2;
            aoff[mi][kk] = rowA*128 + (kb ^ ((rowA & 7) << 4));
            boff[mi][kk] = rowB*128 + (kb ^ ((rowB & 7) << 4));
        }
    }
    f32x4 acc[4][4];
    const f32x4 zz = {0.f, 0.f, 0.f, 0.f};
    #pragma unroll
    for (int mi = 0; mi < 4; mi++)
        #pragma unroll
        for (int ni = 0; ni < 4; ni++) acc[mi][ni] = zz;
    for (int s = 0; s < 36; s++) {
        int tap = s >> 2, kq = s & 3;
        int dy = tap / 3, dx = tap - dy*3;
        const int c0 = kq * 64;
        const int yy = y + dy - 1;
        const bool yok = (yy >= 0) && (yy < HH);
        #pragma unroll
        for (int i = 0; i < 4; i++) {
            int ci = i*256 + tid;
            int row = ci >> 3, pc = ci & 7;
            int kc = pc ^ (row & 7);
            int xx = row + dx - 1;
            u16x8 a;
            if (yok && xx >= 0 && xx < WW) {
                const float* sp = in_f + (((size_t)(b*HH) + yy)*WW + xx)*CIN + c0 + kc*8;
                #pragma unroll
                for (int j = 0; j < 8; j++) a[j] = (short)f2bf(sp[j]);
            } else {
                #pragma unroll
                for (int j = 0; j < 8; j++) a[j] = 0;
            }
            *(u16x8*)(smem + ci*16) = a;
            const float* wsrc = w_f + ((size_t)(tap*CIN + c0 + kc*8))*CO + n0 + row;
            u16x8 bb;
            #pragma unroll
            for (int j = 0; j < 8; j++) bb[j] = (short)f2bf(wsrc[(size_t)j*CO]);
            *(u16x8*)(smemB + ci*16) = bb;
        }
        __syncthreads();
        #pragma unroll
        for (int kk = 0; kk < 2; kk++) {
            bf16x8 av[4], bv[4];
            #pragma unroll
            for (int mi = 0; mi < 4; mi++) av[mi] = *(const bf16x8*)(smem  + aoff[mi][kk]);
            #pragma unroll
            for (int ni = 0; ni < 4; ni++) bv[ni] = *(const bf16x8*)(smemB + boff[ni][kk]);
            #pragma unroll
            for (int mi = 0; mi < 4; mi++)
                #pragma unroll
                for (int ni = 0; ni < 4; ni++)
                    acc[mi][ni] = __builtin_amdgcn_mfma_f32_16x16x32_bf16(
                        av[mi], bv[ni], acc[mi][ni], 0, 0, 0);
        }
        __syncthreads();
    }
    float* shf = smemf;
    float* sW  = smemf + 8448;
    for (int j = tid; j < 128*18; j += 256) {
        int c = j / 18, o = j - c*18;
        sW[c*20 + o] = (o < 6) ? w_cls[(size_t)(n0 + c)*6 + o]
                               : w_dlt[(size_t)(n0 + c)*12 + (o - 6)];
    }
    float bsh[4];
    #pragma unroll
    for (int ni = 0; ni < 4; ni++) bsh[ni] = b_sh[n0 + wc*64 + ni*16 + l15];
    float a18[18];
    #pragma unroll
    for (int o = 0; o < 18; o++) a18[o] = 0.f;
    const int rr = tid & 127, chalf = tid >> 7;
    #pragma unroll
    for (int pass = 0; pass < 2; pass++) {
        if (wc == pass) {
            #pragma unroll
            for (int mi = 0; mi < 4; mi++)
                #pragma unroll
                for (int ni = 0; ni < 4; ni++) {
                    int colL = ni*16 + l15;
                    int row0 = wr*64 + mi*16 + l4*4;
                    f32x4 v = acc[mi][ni];
                    f32x4 sv;
                    #pragma unroll
                    for (int r = 0; r < 4; r++) sv[r] = fmaxf(v[r] + bsh[ni], 0.f);
                    *(f32x4*)(shf + colL*132 + row0) = sv;
                }
        }
        __syncthreads();
        #pragma unroll 4
        for (int i = 0; i < 32; i++) {
            int c = chalf*32 + i;
            float v = shf[c*132 + rr];
            const float* wrow = sW + (pass*64 + c)*20;
            #pragma unroll
            for (int o = 0; o < 18; o++) a18[o] += v * wrow[o];
        }
        __syncthreads();
    }
    const int pixel = mtile*128 + rr;
    float* lo = out + (size_t)pixel*6;
    float* dl = out + DELTA_BASE + (size_t)pixel*12;
    #pragma unroll
    for (int o = 0; o < 6; o++)  atomicAdd(lo + o, a18[o]);
    #pragma unroll
    for (int o = 0; o < 12; o++) atomicAdd(dl + o, a18[6 + o]);
}

__global__ __launch_bounds__(256) void k_finalize(float* __restrict__ out,
                                                  const float* __restrict__ b_cls,
                                                  const float* __restrict__ b_dlt) {
    int pix = blockIdx.x*256 + threadIdx.x;
    if (pix >= NPIX) return;
    float* lo = out + (size_t)pix*6;
    float* pr = out + (size_t)LOGITS_N + (size_t)pix*6;
    float* dl = out + (size_t)DELTA_BASE + (size_t)pix*12;
    #pragma unroll
    for (int a = 0; a < 3; a++) {
        float l0 = lo[a*2]   + b_cls[a*2];
        float l1 = lo[a*2+1] + b_cls[a*2+1];
        lo[a*2] = l0; lo[a*2+1] = l1;
        float m = fmaxf(l0, l1);
        float e0 = __expf(l0 - m), e1 = __expf(l1 - m);
        float inv = 1.f / (e0 + e1);
        pr[a*2] = e0*inv; pr[a*2+1] = e1*inv;
    }
    #pragma unroll
    for (int o = 0; o < 12; o++) dl[o] += b_dlt[o];
}

extern "C" void kernel_launch(void* const* d_in, const int* in_sizes, int n_in,
                              void* d_out, int out_size, void* d_ws, size_t ws_size,
                              hipStream_t stream) {
    const float* in    = (const float*)d_in[0];
    const float* w_sh  = (const float*)d_in[1];
    const float* b_sh  = (const float*)d_in[2];
    const float* w_cls = (const float*)d_in[3];
    const float* b_cls = (const float*)d_in[4];
    const float* w_dlt = (const float*)d_in[5];
    const float* b_dlt = (const float*)d_in[6];
    float* out = (float*)d_out;

    const size_t in_p_elems = (size_t)BATCH*HP*HP*CIN;   // 17,305,600
    const size_t wt_elems   = (size_t)9*CO*CIN;          // 1,179,648
    const size_t part_elems = (size_t)2*NPIX*18;         // 2,359,296
    const size_t need = (in_p_elems + wt_elems)*2 + part_elems*4;  // ~46.4 MB

    if (ws_size >= need) {
        unsigned short* in_p = (unsigned short*)d_ws;
        unsigned short* wt   = in_p + in_p_elems;
        float* part = (float*)(wt + wt_elems);
        hipFuncSetAttribute((const void*)k_main8,
                            hipFuncAttributeMaxDynamicSharedMemorySize, 98304);
        int padq = (int)(((size_t)BATCH*HP*HP*64 + 255)/256);
        k_pad_convert<<<padq, 256, 0, stream>>>(in, in_p);
        k_wt_convert<<<9*CO, 256, 0, stream>>>(w_sh, wt);
        k_main8<<<512, 512, 98304, stream>>>(in_p, wt, b_sh, w_cls, w_dlt, part);
        k_finalize_ws<<<(NPIX + 255)/256, 256, 0, stream>>>(part, out, b_cls, b_dlt);
    } else {
        hipMemsetAsync(d_out, 0, (size_t)out_size * sizeof(float), stream);
        k_main_fb<<<2048, 256, 0, stream>>>(in, w_sh, b_sh, w_cls, w_dlt, out);
        k_finalize<<<(NPIX + 255)/256, 256, 0, stream>>>(out, b_cls, b_dlt);
    }
}

// Round 14
// 194.044 us; speedup vs baseline: 1.4801x; 1.4801x over previous
//
#include <hip/hip_runtime.h>
#include <stdint.h>

#define BATCH 4
#define HH 128
#define WW 128
#define CIN 256
#define CO 512
#define HP 130
#define NPIX (BATCH*HH*WW)          // 65536
#define LOGITS_N (NPIX*6)           // 393216
#define DELTA_BASE (2*LOGITS_N)     // 786432

typedef short bf16x8 __attribute__((ext_vector_type(8)));
typedef unsigned short u16x8 __attribute__((ext_vector_type(8)));
typedef float f32x4 __attribute__((ext_vector_type(4)));
typedef unsigned int u32;

__device__ __forceinline__ unsigned short f2bf(float f) {
    union { float f; unsigned int u; } v; v.f = f;
    return (unsigned short)((v.u + 0x7FFFu + ((v.u >> 16) & 1u)) >> 16);
}

__device__ __forceinline__ void gload16(const unsigned short* g, char* l) {
    __builtin_amdgcn_global_load_lds(
        (const __attribute__((address_space(1))) u32*)g,
        (__attribute__((address_space(3))) u32*)l, 16, 0, 0);
}

// ---- pass 1a: fp32 input -> bf16 with 1-pixel zero halo: [B][130][130][256]
__global__ __launch_bounds__(256) void k_pad_convert(const float* __restrict__ in,
                                                     unsigned short* __restrict__ out) {
    size_t q = (size_t)blockIdx.x*256 + threadIdx.x;     // quad index (4 channels)
    if (q >= (size_t)BATCH*HP*HP*64) return;
    int c4 = ((int)q & 63) * 4;
    int pix = (int)(q >> 6);
    int xx = pix % HP; int t = pix / HP; int yy = t % HP; int b = t / HP;
    ushort4 r = {0, 0, 0, 0};
    if (yy >= 1 && yy <= HH && xx >= 1 && xx <= WW) {
        const float4 v = *(const float4*)(in + (((size_t)(b*HH) + (yy-1))*WW + (xx-1))*CIN + c4);
        r.x = f2bf(v.x); r.y = f2bf(v.y); r.z = f2bf(v.z); r.w = f2bf(v.w);
    }
    *(ushort4*)(out + (size_t)pix*CIN + c4) = r;
}

// ---- pass 1b: w_shared [9][256][512] fp32 -> wT [9][512][256] bf16
__global__ __launch_bounds__(256) void k_wt_convert(const float* __restrict__ w,
                                                    unsigned short* __restrict__ wt) {
    int n = blockIdx.x % CO; int tap = blockIdx.x / CO;
    int c = threadIdx.x;
    wt[((size_t)tap*CO + n)*CIN + c] = f2bf(w[((size_t)tap*CIN + c)*CO + n]);
}

// ==== main: 256x256 tile, 16x16x32 MFMA, HALO-REUSE A ====
// Loop kq(4) outer / tap(9) inner. Per kq: stage the 4-row x 130-px x 64-ch input
// slice ONCE into resident LDS (65 KB); all 9 taps read A-fragments at (dy,dx)
// offsets. B: round-8 double-buffer (32 KB x2). LDS total 129 KiB.
__global__ __launch_bounds__(512, 2) void k_main8(
    const unsigned short* __restrict__ in_p,   // bf16 padded input
    const unsigned short* __restrict__ wt,     // bf16 wT [9][512][256]
    const float* __restrict__ b_sh,
    const float* __restrict__ w_cls,
    const float* __restrict__ w_dlt,
    float* __restrict__ part)                  // [2][NPIX][18]
{
    extern __shared__ char LDS[];
    char* const BB0 = LDS + 66560;             // B buffers: 66560 / 99328

    const int tid  = threadIdx.x;
    const int lane = tid & 63, wave = tid >> 6;
    const int l15  = lane & 15, l4 = lane >> 4;
    const int wm   = wave >> 2, wn = wave & 3;

    // XCD-contiguous bijective swizzle (512 % 8 == 0)
    const int bid   = ((blockIdx.x & 7) << 6) + (blockIdx.x >> 3);
    const int ntile = bid & 1, mtile = bid >> 1;
    const int n0 = ntile << 8;
    const int b  = mtile >> 6;
    const int y0 = (mtile & 63) * 2;           // tile covers image rows y0, y0+1

    // B staging offsets (per thread): chunk tid -> row tid>>3, sub tid&7 (inv XOR on src)
    const int rl0 = tid >> 3, pc0 = tid & 7;
    const int kcB = pc0 ^ (rl0 & 7);
    const int offB = rl0*256 + kcB*8;          // elements
    const int t16 = tid*16;

    // B fragment LDS byte offsets (XOR-swizzled), relative to B buffer
    int base_b[2];
    #pragma unroll
    for (int kk = 0; kk < 2; kk++) {
        int swz = ((kk*32 + l4*8)*2) ^ ((l15 & 7) << 4);
        base_b[kk] = (wn*64 + l15)*128 + swz;
    }

    f32x4 acc[8][4];
    const f32x4 zz = {0.f, 0.f, 0.f, 0.f};
    #pragma unroll
    for (int mi = 0; mi < 8; mi++)
        #pragma unroll
        for (int ni = 0; ni < 4; ni++) acc[mi][ni] = zz;

    // A slice source: pixels Pbase..Pbase+519 are rows y0..y0+3 of image b (contiguous)
    const unsigned short* const Abase = in_p + ((size_t)(b*HP) + y0) * HP * 256;

#define STAGE_A(KQ)                                                            \
    {                                                                          \
        _Pragma("unroll")                                                      \
        for (int i = 0; i < 8; i++) {                                          \
            int ct = i*512 + tid;                                              \
            int p = ct >> 3, pc = ct & 7, kc = pc ^ (p & 7);                   \
            gload16(Abase + (size_t)p*256 + (KQ)*64 + kc*8, LDS + ct*16);      \
        }                                                                      \
        if (tid < 64) {                                                        \
            int ct = 4096 + tid;                                               \
            int p = ct >> 3, pc = ct & 7, kc = pc ^ (p & 7);                   \
            gload16(Abase + (size_t)p*256 + (KQ)*64 + kc*8, LDS + ct*16);      \
        }                                                                      \
    }

    // ---- prologue: stage A(kq=0) + B(g=0), drain, barrier
    STAGE_A(0)
    {
        const unsigned short* gB = wt + (size_t)n0*256;   // tap0, kq0
        gload16(gB + offB,          BB0 + t16);
        gload16(gB + 16384 + offB,  BB0 + 8192 + t16);
        gload16(gB + 32768 + offB,  BB0 + 16384 + t16);
        gload16(gB + 49152 + offB,  BB0 + 24576 + t16);
    }
    asm volatile("s_waitcnt vmcnt(0)" ::: "memory");
    __builtin_amdgcn_sched_barrier(0);
    __builtin_amdgcn_s_barrier();
    __builtin_amdgcn_sched_barrier(0);

#define MFMA_Q(Q, AQ)                                                        \
    __builtin_amdgcn_s_setprio(1);                                           \
    _Pragma("unroll")                                                        \
    for (int kk = 0; kk < 2; kk++)                                           \
        _Pragma("unroll")                                                    \
        for (int mm = 0; mm < 2; mm++)                                       \
            _Pragma("unroll")                                                \
            for (int ni = 0; ni < 4; ni++)                                   \
                acc[2*(Q)+mm][ni] = __builtin_amdgcn_mfma_f32_16x16x32_bf16( \
                    AQ[mm][kk], breg[ni][kk], acc[2*(Q)+mm][ni], 0, 0, 0);   \
    __builtin_amdgcn_s_setprio(0);

#define LOAD_Q(AQ, Q)                                                        \
    _Pragma("unroll")                                                        \
    for (int kk = 0; kk < 2; kk++) {                                         \
        AQ[0][kk] = *(const bf16x8*)(LDS + (kk ? baseA1 : baseA0) + (2*(Q))*2048);   \
        AQ[1][kk] = *(const bf16x8*)(LDS + (kk ? baseA1 : baseA0) + (2*(Q)+1)*2048); \
    }

    for (int kq = 0; kq < 4; kq++) {
        #pragma unroll
        for (int tap = 0; tap < 9; tap++) {
            const int dy = tap / 3, dx = tap - dy*3;            // compile-time
            const int g  = kq*9 + tap;
            const int tap1 = (tap == 8) ? 0 : tap + 1;
            const int kq1  = (tap == 8) ? kq + 1 : kq;
            const unsigned short* gB = wt + ((size_t)(tap1*512 + n0))*256 + kq1*64;
            const char* bufB = BB0 + ((g & 1) << 15);
            char* Bd = BB0 + (((g + 1) & 1) << 15);
            const bool more = (g < 35);

            // A per-lane addressing for this tap: p = (dy+wm)*130 + dx + l15 + mi*16
            // (mi*16 ≡ 0 mod 8 -> p&7 constant across mi,kk)
            const int pl = (dy + wm)*130 + dx + l15;
            const int plb = pl << 7;
            const int sw = (pl & 7) << 4;
            const int baseA0 = plb + ((l4*16) ^ sw);            // kk=0: kb = l4*16
            const int baseA1 = plb + ((64 + l4*16) ^ sw);       // kk=1: kb = 64+l4*16

            // stage B(g+1) up front (full-step slack)
            if (more) {
                gload16(gB + offB,          Bd + t16);
                gload16(gB + 16384 + offB,  Bd + 8192 + t16);
                gload16(gB + 32768 + offB,  Bd + 16384 + t16);
                gload16(gB + 49152 + offB,  Bd + 24576 + t16);
            }
            __builtin_amdgcn_sched_barrier(0);

            // B fragments (current buffer)
            bf16x8 breg[4][2];
            #pragma unroll
            for (int kk = 0; kk < 2; kk++) {
                breg[0][kk] = *(const bf16x8*)(bufB + base_b[kk]);
                breg[1][kk] = *(const bf16x8*)(bufB + base_b[kk] + 2048);
                breg[2][kk] = *(const bf16x8*)(bufB + base_b[kk] + 4096);
                breg[3][kk] = *(const bf16x8*)(bufB + base_b[kk] + 6144);
            }
            // A quads with read-ahead (A resident in LDS; no gating needed)
            bf16x8 a0[2][2], a1[2][2], a2[2][2], a3[2][2];
            LOAD_Q(a0, 0)
            LOAD_Q(a1, 1)
            MFMA_Q(0, a0)
            LOAD_Q(a2, 2)
            MFMA_Q(1, a1)
            LOAD_Q(a3, 3)
            MFMA_Q(2, a2)
            MFMA_Q(3, a3)

            // boundary: B(g+1) landed (only outstanding loads); all bufB reads retired
            if (more) { asm volatile("s_waitcnt vmcnt(0)" ::: "memory"); }
            __builtin_amdgcn_sched_barrier(0);
            __builtin_amdgcn_s_barrier();
            __builtin_amdgcn_sched_barrier(0);
        }
        // kq boundary: re-stage resident A slice for kq+1 (all A reads retired above)
        if (kq < 3) {
            STAGE_A(kq + 1)
            asm volatile("s_waitcnt vmcnt(0)" ::: "memory");
            __builtin_amdgcn_sched_barrier(0);
            __builtin_amdgcn_s_barrier();
            __builtin_amdgcn_sched_barrier(0);
        }
    }
#undef MFMA_Q
#undef LOAD_Q
#undef STAGE_A

    // ---- epilogue: bias+ReLU + 1x1-head partial reduction over this block's 256 channels
    float* shf = (float*)LDS;                  // [64 cols][260] = 66560 B
    float* sW  = (float*)(LDS + 66560);        // [256][20] = 20480 B
    for (int j = tid; j < 256*18; j += 512) {
        int c = j / 18, o = j - c*18;
        sW[c*20 + o] = (o < 6) ? w_cls[(size_t)(n0 + c)*6 + o]
                               : w_dlt[(size_t)(n0 + c)*12 + (o - 6)];
    }
    float bsh[4];
    #pragma unroll
    for (int ni = 0; ni < 4; ni++) bsh[ni] = b_sh[n0 + wn*64 + ni*16 + l15];

    float a18[18];
    #pragma unroll
    for (int o = 0; o < 18; o++) a18[o] = 0.f;
    const int rr = tid & 255, chalf = tid >> 8;
    __syncthreads();

    for (int p = 0; p < 4; ++p) {
        if (wn == p) {
            #pragma unroll
            for (int mi = 0; mi < 8; mi++)
                #pragma unroll
                for (int ni = 0; ni < 4; ni++) {
                    int colL = ni*16 + l15;
                    int row0 = wm*128 + mi*16 + l4*4;
                    f32x4 v = acc[mi][ni];
                    f32x4 sv;
                    #pragma unroll
                    for (int r = 0; r < 4; r++) sv[r] = fmaxf(v[r] + bsh[ni], 0.f);
                    *(f32x4*)(shf + colL*260 + row0) = sv;
                }
        }
        __syncthreads();
        #pragma unroll 4
        for (int i = 0; i < 32; i++) {
            int c = chalf*32 + i;
            float v = shf[c*260 + rr];
            const float* wrow = sW + (p*64 + c)*20;
            #pragma unroll
            for (int o = 0; o < 18; o++) a18[o] += v * wrow[o];
        }
        __syncthreads();
    }

    if (chalf == 1) {
        #pragma unroll
        for (int o = 0; o < 18; o++) shf[rr*18 + o] = a18[o];
    }
    __syncthreads();
    if (chalf == 0) {
        float* dst = part + ((size_t)ntile*NPIX + (size_t)mtile*256 + rr)*18;
        #pragma unroll
        for (int o = 0; o < 18; o++) dst[o] = a18[o] + shf[rr*18 + o];
    }
}

// ---- finalize (ws path): sum 2 partials, biases, softmax -> all outputs
__global__ __launch_bounds__(256) void k_finalize_ws(const float* __restrict__ part,
                                                     float* __restrict__ out,
                                                     const float* __restrict__ b_cls,
                                                     const float* __restrict__ b_dlt) {
    int pix = blockIdx.x*256 + threadIdx.x;
    if (pix >= NPIX) return;
    float s[18];
    #pragma unroll
    for (int o = 0; o < 18; o++)
        s[o] = part[(size_t)pix*18 + o] + part[((size_t)NPIX + pix)*18 + o];
    float* lo = out + (size_t)pix*6;
    float* pr = out + (size_t)LOGITS_N + (size_t)pix*6;
    float* dl = out + (size_t)DELTA_BASE + (size_t)pix*12;
    #pragma unroll
    for (int a = 0; a < 3; a++) {
        float l0 = s[a*2]   + b_cls[a*2];
        float l1 = s[a*2+1] + b_cls[a*2+1];
        lo[a*2] = l0; lo[a*2+1] = l1;
        float m = fmaxf(l0, l1);
        float e0 = __expf(l0 - m), e1 = __expf(l1 - m);
        float inv = 1.f / (e0 + e1);
        pr[a*2] = e0*inv; pr[a*2+1] = e1*inv;
    }
    #pragma unroll
    for (int o = 0; o < 12; o++) dl[o] = s[6 + o] + b_dlt[o];
}

// ======== fallback path (no workspace): round-2 proven kernel, atomics ========
__global__ __launch_bounds__(256) void k_main_fb(
    const float* __restrict__ in_f, const float* __restrict__ w_f,
    const float* __restrict__ b_sh, const float* __restrict__ w_cls,
    const float* __restrict__ w_dlt, float* __restrict__ out)
{
    __shared__ float smemf[11008];
    char* smem  = (char*)smemf;
    char* smemB = smem + 16384;
    const int tid = threadIdx.x;
    const int lane = tid & 63, wave = tid >> 6;
    const int l15 = lane & 15, l4 = lane >> 4;
    const int wr = wave >> 1, wc = wave & 1;
    int bid = ((blockIdx.x & 7) << 8) + (blockIdx.x >> 3);
    const int ntile = bid & 3, mtile = bid >> 2;
    const int n0 = ntile << 7;
    const int b = mtile >> 7, y = mtile & 127;
    int aoff[4][2], boff[4][2];
    #pragma unroll
    for (int mi = 0; mi < 4; mi++) {
        int rowA = wr*64 + mi*16 + l15;
        int rowB = wc*64 + mi*16 + l15;
        #pragma unroll
        for (int kk = 0; kk < 2; kk++) {
            int kb = (kk*32 + l4*8) * 2;
            aoff[mi][kk] = rowA*128 + (kb ^ ((rowA & 7) << 4));
            boff[mi][kk] = rowB*128 + (kb ^ ((rowB & 7) << 4));
        }
    }
    f32x4 acc[4][4];
    const f32x4 zz = {0.f, 0.f, 0.f, 0.f};
    #pragma unroll
    for (int mi = 0; mi < 4; mi++)
        #pragma unroll
        for (int ni = 0; ni < 4; ni++) acc[mi][ni] = zz;
    for (int s = 0; s < 36; s++) {
        int tap = s >> 2, kq = s & 3;
        int dy = tap / 3, dx = tap - dy*3;
        const int c0 = kq * 64;
        const int yy = y + dy - 1;
        const bool yok = (yy >= 0) && (yy < HH);
        #pragma unroll
        for (int i = 0; i < 4; i++) {
            int ci = i*256 + tid;
            int row = ci >> 3, pc = ci & 7;
            int kc = pc ^ (row & 7);
            int xx = row + dx - 1;
            u16x8 a;
            if (yok && xx >= 0 && xx < WW) {
                const float* sp = in_f + (((size_t)(b*HH) + yy)*WW + xx)*CIN + c0 + kc*8;
                #pragma unroll
                for (int j = 0; j < 8; j++) a[j] = (short)f2bf(sp[j]);
            } else {
                #pragma unroll
                for (int j = 0; j < 8; j++) a[j] = 0;
            }
            *(u16x8*)(smem + ci*16) = a;
            const float* wsrc = w_f + ((size_t)(tap*CIN + c0 + kc*8))*CO + n0 + row;
            u16x8 bb;
            #pragma unroll
            for (int j = 0; j < 8; j++) bb[j] = (short)f2bf(wsrc[(size_t)j*CO]);
            *(u16x8*)(smemB + ci*16) = bb;
        }
        __syncthreads();
        #pragma unroll
        for (int kk = 0; kk < 2; kk++) {
            bf16x8 av[4], bv[4];
            #pragma unroll
            for (int mi = 0; mi < 4; mi++) av[mi] = *(const bf16x8*)(smem  + aoff[mi][kk]);
            #pragma unroll
            for (int ni = 0; ni < 4; ni++) bv[ni] = *(const bf16x8*)(smemB + boff[ni][kk]);
            #pragma unroll
            for (int mi = 0; mi < 4; mi++)
                #pragma unroll
                for (int ni = 0; ni < 4; ni++)
                    acc[mi][ni] = __builtin_amdgcn_mfma_f32_16x16x32_bf16(
                        av[mi], bv[ni], acc[mi][ni], 0, 0, 0);
        }
        __syncthreads();
    }
    float* shf = smemf;
    float* sW  = smemf + 8448;
    for (int j = tid; j < 128*18; j += 256) {
        int c = j / 18, o = j - c*18;
        sW[c*20 + o] = (o < 6) ? w_cls[(size_t)(n0 + c)*6 + o]
                               : w_dlt[(size_t)(n0 + c)*12 + (o - 6)];
    }
    float bsh[4];
    #pragma unroll
    for (int ni = 0; ni < 4; ni++) bsh[ni] = b_sh[n0 + wc*64 + ni*16 + l15];
    float a18[18];
    #pragma unroll
    for (int o = 0; o < 18; o++) a18[o] = 0.f;
    const int rr = tid & 127, chalf = tid >> 7;
    #pragma unroll
    for (int pass = 0; pass < 2; pass++) {
        if (wc == pass) {
            #pragma unroll
            for (int mi = 0; mi < 4; mi++)
                #pragma unroll
                for (int ni = 0; ni < 4; ni++) {
                    int colL = ni*16 + l15;
                    int row0 = wr*64 + mi*16 + l4*4;
                    f32x4 v = acc[mi][ni];
                    f32x4 sv;
                    #pragma unroll
                    for (int r = 0; r < 4; r++) sv[r] = fmaxf(v[r] + bsh[ni], 0.f);
                    *(f32x4*)(shf + colL*132 + row0) = sv;
                }
        }
        __syncthreads();
        #pragma unroll 4
        for (int i = 0; i < 32; i++) {
            int c = chalf*32 + i;
            float v = shf[c*132 + rr];
            const float* wrow = sW + (pass*64 + c)*20;
            #pragma unroll
            for (int o = 0; o < 18; o++) a18[o] += v * wrow[o];
        }
        __syncthreads();
    }
    const int pixel = mtile*128 + rr;
    float* lo = out + (size_t)pixel*6;
    float* dl = out + DELTA_BASE + (size_t)pixel*12;
    #pragma unroll
    for (int o = 0; o < 6; o++)  atomicAdd(lo + o, a18[o]);
    #pragma unroll
    for (int o = 0; o < 12; o++) atomicAdd(dl + o, a18[6 + o]);
}

__global__ __launch_bounds__(256) void k_finalize(float* __restrict__ out,
                                                  const float* __restrict__ b_cls,
                                                  const float* __restrict__ b_dlt) {
    int pix = blockIdx.x*256 + threadIdx.x;
    if (pix >= NPIX) return;
    float* lo = out + (size_t)pix*6;
    float* pr = out + (size_t)LOGITS_N + (size_t)pix*6;
    float* dl = out + (size_t)DELTA_BASE + (size_t)pix*12;
    #pragma unroll
    for (int a = 0; a < 3; a++) {
        float l0 = lo[a*2]   + b_cls[a*2];
        float l1 = lo[a*2+1] + b_cls[a*2+1];
        lo[a*2] = l0; lo[a*2+1] = l1;
        float m = fmaxf(l0, l1);
        float e0 = __expf(l0 - m), e1 = __expf(l1 - m);
        float inv = 1.f / (e0 + e1);
        pr[a*2] = e0*inv; pr[a*2+1] = e1*inv;
    }
    #pragma unroll
    for (int o = 0; o < 12; o++) dl[o] += b_dlt[o];
}

extern "C" void kernel_launch(void* const* d_in, const int* in_sizes, int n_in,
                              void* d_out, int out_size, void* d_ws, size_t ws_size,
                              hipStream_t stream) {
    const float* in    = (const float*)d_in[0];
    const float* w_sh  = (const float*)d_in[1];
    const float* b_sh  = (const float*)d_in[2];
    const float* w_cls = (const float*)d_in[3];
    const float* b_cls = (const float*)d_in[4];
    const float* w_dlt = (const float*)d_in[5];
    const float* b_dlt = (const float*)d_in[6];
    float* out = (float*)d_out;

    const size_t in_p_elems = (size_t)BATCH*HP*HP*CIN;   // 17,305,600
    const size_t wt_elems   = (size_t)9*CO*CIN;          // 1,179,648
    const size_t part_elems = (size_t)2*NPIX*18;         // 2,359,296
    const size_t need = (in_p_elems + wt_elems)*2 + part_elems*4;  // ~46.4 MB

    if (ws_size >= need) {
        unsigned short* in_p = (unsigned short*)d_ws;
        unsigned short* wt   = in_p + in_p_elems;
        float* part = (float*)(wt + wt_elems);
        hipFuncSetAttribute((const void*)k_main8,
                            hipFuncAttributeMaxDynamicSharedMemorySize, 132096);
        int padq = (int)(((size_t)BATCH*HP*HP*64 + 255)/256);
        k_pad_convert<<<padq, 256, 0, stream>>>(in, in_p);
        k_wt_convert<<<9*CO, 256, 0, stream>>>(w_sh, wt);
        k_main8<<<512, 512, 132096, stream>>>(in_p, wt, b_sh, w_cls, w_dlt, part);
        k_finalize_ws<<<(NPIX + 255)/256, 256, 0, stream>>>(part, out, b_cls, b_dlt);
    } else {
        hipMemsetAsync(d_out, 0, (size_t)out_size * sizeof(float), stream);
        k_main_fb<<<2048, 256, 0, stream>>>(in, w_sh, b_sh, w_cls, w_dlt, out);
        k_finalize<<<(NPIX + 255)/256, 256, 0, stream>>>(out, b_cls, b_dlt);
    }
}

// Round 15
// 192.518 us; speedup vs baseline: 1.4918x; 1.0079x over previous
//
#include <hip/hip_runtime.h>
#include <stdint.h>

#define BATCH 4
#define HH 128
#define WW 128
#define CIN 256
#define CO 512
#define HP 130
#define NPIX (BATCH*HH*WW)          // 65536
#define LOGITS_N (NPIX*6)           // 393216
#define DELTA_BASE (2*LOGITS_N)     // 786432

typedef short bf16x8 __attribute__((ext_vector_type(8)));
typedef unsigned short u16x8 __attribute__((ext_vector_type(8)));
typedef float f32x4 __attribute__((ext_vector_type(4)));
typedef unsigned int u32;

__device__ __forceinline__ unsigned short f2bf(float f) {
    union { float f; unsigned int u; } v; v.f = f;
    return (unsigned short)((v.u + 0x7FFFu + ((v.u >> 16) & 1u)) >> 16);
}

__device__ __forceinline__ void gload16(const unsigned short* g, char* l) {
    __builtin_amdgcn_global_load_lds(
        (const __attribute__((address_space(1))) u32*)g,
        (__attribute__((address_space(3))) u32*)l, 16, 0, 0);
}

// ---- pass 1a: fp32 input -> bf16 with 1-pixel zero halo: [B][130][130][256]
__global__ __launch_bounds__(256) void k_pad_convert(const float* __restrict__ in,
                                                     unsigned short* __restrict__ out) {
    size_t q = (size_t)blockIdx.x*256 + threadIdx.x;     // quad index (4 channels)
    if (q >= (size_t)BATCH*HP*HP*64) return;
    int c4 = ((int)q & 63) * 4;
    int pix = (int)(q >> 6);
    int xx = pix % HP; int t = pix / HP; int yy = t % HP; int b = t / HP;
    ushort4 r = {0, 0, 0, 0};
    if (yy >= 1 && yy <= HH && xx >= 1 && xx <= WW) {
        const float4 v = *(const float4*)(in + (((size_t)(b*HH) + (yy-1))*WW + (xx-1))*CIN + c4);
        r.x = f2bf(v.x); r.y = f2bf(v.y); r.z = f2bf(v.z); r.w = f2bf(v.w);
    }
    *(ushort4*)(out + (size_t)pix*CIN + c4) = r;
}

// ---- pass 1b: w_shared [9][256][512] fp32 -> wT [9][512][256] bf16
__global__ __launch_bounds__(256) void k_wt_convert(const float* __restrict__ w,
                                                    unsigned short* __restrict__ wt) {
    int n = blockIdx.x % CO; int tap = blockIdx.x / CO;
    int c = threadIdx.x;
    wt[((size_t)tap*CO + n)*CIN + c] = f2bf(w[((size_t)tap*CIN + c)*CO + n]);
}

// ==== main: 256x256 tile, 16x16x32 MFMA, depth-2 A pipeline (round-12 best) ====
// A: TRIPLE buffer (LDS 0/32K/64K), staged 2 steps ahead -> no mid-step wait.
// B: double buffer (LDS 96K/128K), staged 1 step ahead.
// One boundary vmcnt(4) + barrier per step. LDS = 160 KiB exactly.
__global__ __launch_bounds__(512, 2) void k_main8(
    const unsigned short* __restrict__ in_p,   // bf16 padded input
    const unsigned short* __restrict__ wt,     // bf16 wT [9][512][256]
    const float* __restrict__ b_sh,
    const float* __restrict__ w_cls,
    const float* __restrict__ w_dlt,
    float* __restrict__ part)                  // [2][NPIX][18]
{
    extern __shared__ char LDS[];
    char* const BBASE = LDS + 98304;

    const int tid  = threadIdx.x;
    const int lane = tid & 63, wave = tid >> 6;
    const int l15  = lane & 15, l4 = lane >> 4;
    const int wm   = wave >> 2, wn = wave & 3;

    // XCD-contiguous bijective swizzle (512 % 8 == 0)
    const int bid   = ((blockIdx.x & 7) << 6) + (blockIdx.x >> 3);
    const int ntile = bid & 1, mtile = bid >> 1;
    const int n0 = ntile << 8;
    const int b  = mtile >> 6;
    const int y0 = (mtile & 63) * 2;           // tile covers image rows y0, y0+1

    // per-thread staging offset: chunk tid -> row tid>>3, sub tid&7 (inverse XOR on source)
    const int rl0 = tid >> 3, pc0 = tid & 7;
    const int kc0 = pc0 ^ (rl0 & 7);
    const int off = rl0*256 + kc0*8;           // elements
    const int t16 = tid*16;                    // LDS dest byte offset

    // MFMA fragment LDS byte offsets (XOR-swizzled reads), relative to each buffer
    int base_a[2], base_b[2];
    #pragma unroll
    for (int kk = 0; kk < 2; kk++) {
        int swz = ((kk*32 + l4*8)*2) ^ ((l15 & 7) << 4);
        base_a[kk] = (wm*128 + l15)*128 + swz;
        base_b[kk] = (wn*64 + l15)*128 + swz;
    }

    f32x4 acc[8][4];
    const f32x4 zz = {0.f, 0.f, 0.f, 0.f};
    #pragma unroll
    for (int mi = 0; mi < 8; mi++)
        #pragma unroll
        for (int ni = 0; ni < 4; ni++) acc[mi][ni] = zz;

    // ---- prologue: stage A(0) -> Abuf0, B(0) -> Bbuf0, A(1) -> Abuf1
    {
        const unsigned short* gA0 = in_p + ((size_t)(b*HP + y0))*HP*256;       // tap0,kq0
        const unsigned short* gB0 = wt + (size_t)n0*256;
        const unsigned short* gA1 = gA0 + 64;                                  // tap0,kq1
        gload16(gA0 + off,          LDS + t16);
        gload16(gA0 + 16384 + off,  LDS + 8192 + t16);
        gload16(gA0 + 33280 + off,  LDS + 16384 + t16);
        gload16(gA0 + 49664 + off,  LDS + 24576 + t16);
        __builtin_amdgcn_sched_barrier(0);
        gload16(gB0 + off,          BBASE + t16);
        gload16(gB0 + 16384 + off,  BBASE + 8192 + t16);
        gload16(gB0 + 32768 + off,  BBASE + 16384 + t16);
        gload16(gB0 + 49152 + off,  BBASE + 24576 + t16);
        __builtin_amdgcn_sched_barrier(0);
        gload16(gA1 + off,          LDS + 32768 + t16);
        gload16(gA1 + 16384 + off,  LDS + 40960 + t16);
        gload16(gA1 + 33280 + off,  LDS + 49152 + t16);
        gload16(gA1 + 49664 + off,  LDS + 57344 + t16);
    }
    asm volatile("s_waitcnt vmcnt(4)" ::: "memory");      // A(0)+B(0) landed; A(1) may fly
    __builtin_amdgcn_sched_barrier(0);
    __builtin_amdgcn_s_barrier();
    __builtin_amdgcn_sched_barrier(0);

#define MFMA_Q(Q, AQ)                                                        \
    __builtin_amdgcn_s_setprio(1);                                           \
    _Pragma("unroll")                                                        \
    for (int kk = 0; kk < 2; kk++)                                           \
        _Pragma("unroll")                                                    \
        for (int mm = 0; mm < 2; mm++)                                       \
            _Pragma("unroll")                                                \
            for (int ni = 0; ni < 4; ni++)                                   \
                acc[2*(Q)+mm][ni] = __builtin_amdgcn_mfma_f32_16x16x32_bf16( \
                    AQ[mm][kk], breg[ni][kk], acc[2*(Q)+mm][ni], 0, 0, 0);   \
    __builtin_amdgcn_s_setprio(0);

#define LOAD_Q(AQ, Q)                                                        \
    _Pragma("unroll")                                                        \
    for (int kk = 0; kk < 2; kk++) {                                         \
        AQ[0][kk] = *(const bf16x8*)(bufA + base_a[kk] + (2*(Q))*2048);      \
        AQ[1][kk] = *(const bf16x8*)(bufA + base_a[kk] + (2*(Q)+1)*2048);    \
    }

    int ia = 0;                                 // A read buffer index (s % 3)
    for (int s = 0; s < 36; ++s) {
        // B(s+1) source
        const int s1 = s + 1;
        const int tapB = s1 >> 2, kqB = s1 & 3;
        const unsigned short* gB = wt + ((size_t)(tapB*512 + n0))*256 + kqB*64;
        // A(s+2) source
        const int s2p = s + 2;
        const int tapA = s2p >> 2, kqA = s2p & 3;
        const int dyA = (tapA*11) >> 5, dxA = tapA - dyA*3;
        const unsigned short* gA = in_p + ((size_t)((b*HP + y0 + dyA)*HP + dxA))*256 + kqA*64;

        const char* bufA = LDS + (ia << 15);
        const char* bufB = BBASE + ((s & 1) << 15);
        int iw = ia + 2; if (iw > 2) iw -= 3;
        char* Ad = LDS + (iw << 15);
        char* Bd = BBASE + ((s1 & 1) << 15);
        const bool moreB = (s < 35), moreA = (s < 34);

        bf16x8 breg[4][2];
        #pragma unroll
        for (int kk = 0; kk < 2; kk++) {
            breg[0][kk] = *(const bf16x8*)(bufB + base_b[kk]);
            breg[1][kk] = *(const bf16x8*)(bufB + base_b[kk] + 2048);
            breg[2][kk] = *(const bf16x8*)(bufB + base_b[kk] + 4096);
            breg[3][kk] = *(const bf16x8*)(bufB + base_b[kk] + 6144);
        }
        bf16x8 a0[2][2], a1[2][2], a2[2][2], a3[2][2];
        LOAD_Q(a0, 0)
        __builtin_amdgcn_sched_barrier(0);
        if (moreB) {
            gload16(gB + off,          Bd + t16);
            gload16(gB + 16384 + off,  Bd + 8192 + t16);
            gload16(gB + 32768 + off,  Bd + 16384 + t16);
            gload16(gB + 49152 + off,  Bd + 24576 + t16);
        }
        __builtin_amdgcn_sched_barrier(0);
        LOAD_Q(a1, 1)
        MFMA_Q(0, a0)
        LOAD_Q(a2, 2)
        if (moreA) {
            gload16(gA + off,          Ad + t16);
            gload16(gA + 16384 + off,  Ad + 8192 + t16);
            gload16(gA + 33280 + off,  Ad + 16384 + t16);
            gload16(gA + 49664 + off,  Ad + 24576 + t16);
        }
        __builtin_amdgcn_sched_barrier(0);
        MFMA_Q(1, a1)
        LOAD_Q(a3, 3)
        MFMA_Q(2, a2)
        MFMA_Q(3, a3)

        // boundary: A(s+1)+B(s+1) landed; A(s+2) (4 loads) may fly
        if (moreA)      { asm volatile("s_waitcnt vmcnt(4)" ::: "memory"); }
        else if (moreB) { asm volatile("s_waitcnt vmcnt(0)" ::: "memory"); }
        __builtin_amdgcn_sched_barrier(0);
        __builtin_amdgcn_s_barrier();
        __builtin_amdgcn_sched_barrier(0);

        ia = ia == 2 ? 0 : ia + 1;
    }
#undef MFMA_Q
#undef LOAD_Q

    // ---- epilogue: bias+ReLU + 1x1-head partial reduction over this block's 256 channels
    float* shf = (float*)LDS;                  // [64 cols][260]
    float* sW  = (float*)(LDS + 66560);        // [256][20]
    for (int j = tid; j < 256*18; j += 512) {
        int c = j / 18, o = j - c*18;
        sW[c*20 + o] = (o < 6) ? w_cls[(size_t)(n0 + c)*6 + o]
                               : w_dlt[(size_t)(n0 + c)*12 + (o - 6)];
    }
    float bsh[4];
    #pragma unroll
    for (int ni = 0; ni < 4; ni++) bsh[ni] = b_sh[n0 + wn*64 + ni*16 + l15];

    float a18[18];
    #pragma unroll
    for (int o = 0; o < 18; o++) a18[o] = 0.f;
    const int rr = tid & 255, chalf = tid >> 8;
    __syncthreads();

    for (int p = 0; p < 4; ++p) {
        if (wn == p) {
            #pragma unroll
            for (int mi = 0; mi < 8; mi++)
                #pragma unroll
                for (int ni = 0; ni < 4; ni++) {
                    int colL = ni*16 + l15;
                    int row0 = wm*128 + mi*16 + l4*4;
                    f32x4 v = acc[mi][ni];
                    f32x4 sv;
                    #pragma unroll
                    for (int r = 0; r < 4; r++) sv[r] = fmaxf(v[r] + bsh[ni], 0.f);
                    *(f32x4*)(shf + colL*260 + row0) = sv;
                }
        }
        __syncthreads();
        #pragma unroll 4
        for (int i = 0; i < 32; i++) {
            int c = chalf*32 + i;
            float v = shf[c*260 + rr];
            const float* wrow = sW + (p*64 + c)*20;
            #pragma unroll
            for (int o = 0; o < 18; o++) a18[o] += v * wrow[o];
        }
        __syncthreads();
    }

    if (chalf == 1) {
        #pragma unroll
        for (int o = 0; o < 18; o++) shf[rr*18 + o] = a18[o];
    }
    __syncthreads();
    if (chalf == 0) {
        float* dst = part + ((size_t)ntile*NPIX + (size_t)mtile*256 + rr)*18;
        #pragma unroll
        for (int o = 0; o < 18; o++) dst[o] = a18[o] + shf[rr*18 + o];
    }
}

// ---- finalize (ws path): sum 2 partials, biases, softmax -> all outputs
__global__ __launch_bounds__(256) void k_finalize_ws(const float* __restrict__ part,
                                                     float* __restrict__ out,
                                                     const float* __restrict__ b_cls,
                                                     const float* __restrict__ b_dlt) {
    int pix = blockIdx.x*256 + threadIdx.x;
    if (pix >= NPIX) return;
    float s[18];
    #pragma unroll
    for (int o = 0; o < 18; o++)
        s[o] = part[(size_t)pix*18 + o] + part[((size_t)NPIX + pix)*18 + o];
    float* lo = out + (size_t)pix*6;
    float* pr = out + (size_t)LOGITS_N + (size_t)pix*6;
    float* dl = out + (size_t)DELTA_BASE + (size_t)pix*12;
    #pragma unroll
    for (int a = 0; a < 3; a++) {
        float l0 = s[a*2]   + b_cls[a*2];
        float l1 = s[a*2+1] + b_cls[a*2+1];
        lo[a*2] = l0; lo[a*2+1] = l1;
        float m = fmaxf(l0, l1);
        float e0 = __expf(l0 - m), e1 = __expf(l1 - m);
        float inv = 1.f / (e0 + e1);
        pr[a*2] = e0*inv; pr[a*2+1] = e1*inv;
    }
    #pragma unroll
    for (int o = 0; o < 12; o++) dl[o] = s[6 + o] + b_dlt[o];
}

// ======== fallback path (no workspace): round-2 proven kernel, atomics ========
__global__ __launch_bounds__(256) void k_main_fb(
    const float* __restrict__ in_f, const float* __restrict__ w_f,
    const float* __restrict__ b_sh, const float* __restrict__ w_cls,
    const float* __restrict__ w_dlt, float* __restrict__ out)
{
    __shared__ float smemf[11008];
    char* smem  = (char*)smemf;
    char* smemB = smem + 16384;
    const int tid = threadIdx.x;
    const int lane = tid & 63, wave = tid >> 6;
    const int l15 = lane & 15, l4 = lane >> 4;
    const int wr = wave >> 1, wc = wave & 1;
    int bid = ((blockIdx.x & 7) << 8) + (blockIdx.x >> 3);
    const int ntile = bid & 3, mtile = bid >> 2;
    const int n0 = ntile << 7;
    const int b = mtile >> 7, y = mtile & 127;
    int aoff[4][2], boff[4][2];
    #pragma unroll
    for (int mi = 0; mi < 4; mi++) {
        int rowA = wr*64 + mi*16 + l15;
        int rowB = wc*64 + mi*16 + l15;
        #pragma unroll
        for (int kk = 0; kk < 2; kk++) {
            int kb = (kk*32 + l4*8) * 2;
            aoff[mi][kk] = rowA*128 + (kb ^ ((rowA & 7) << 4));
            boff[mi][kk] = rowB*128 + (kb ^ ((rowB & 7) << 4));
        }
    }
    f32x4 acc[4][4];
    const f32x4 zz = {0.f, 0.f, 0.f, 0.f};
    #pragma unroll
    for (int mi = 0; mi < 4; mi++)
        #pragma unroll
        for (int ni = 0; ni < 4; ni++) acc[mi][ni] = zz;
    for (int s = 0; s < 36; s++) {
        int tap = s >> 2, kq = s & 3;
        int dy = tap / 3, dx = tap - dy*3;
        const int c0 = kq * 64;
        const int yy = y + dy - 1;
        const bool yok = (yy >= 0) && (yy < HH);
        #pragma unroll
        for (int i = 0; i < 4; i++) {
            int ci = i*256 + tid;
            int row = ci >> 3, pc = ci & 7;
            int kc = pc ^ (row & 7);
            int xx = row + dx - 1;
            u16x8 a;
            if (yok && xx >= 0 && xx < WW) {
                const float* sp = in_f + (((size_t)(b*HH) + yy)*WW + xx)*CIN + c0 + kc*8;
                #pragma unroll
                for (int j = 0; j < 8; j++) a[j] = (short)f2bf(sp[j]);
            } else {
                #pragma unroll
                for (int j = 0; j < 8; j++) a[j] = 0;
            }
            *(u16x8*)(smem + ci*16) = a;
            const float* wsrc = w_f + ((size_t)(tap*CIN + c0 + kc*8))*CO + n0 + row;
            u16x8 bb;
            #pragma unroll
            for (int j = 0; j < 8; j++) bb[j] = (short)f2bf(wsrc[(size_t)j*CO]);
            *(u16x8*)(smemB + ci*16) = bb;
        }
        __syncthreads();
        #pragma unroll
        for (int kk = 0; kk < 2; kk++) {
            bf16x8 av[4], bv[4];
            #pragma unroll
            for (int mi = 0; mi < 4; mi++) av[mi] = *(const bf16x8*)(smem  + aoff[mi][kk]);
            #pragma unroll
            for (int ni = 0; ni < 4; ni++) bv[ni] = *(const bf16x8*)(smemB + boff[ni][kk]);
            #pragma unroll
            for (int mi = 0; mi < 4; mi++)
                #pragma unroll
                for (int ni = 0; ni < 4; ni++)
                    acc[mi][ni] = __builtin_amdgcn_mfma_f32_16x16x32_bf16(
                        av[mi], bv[ni], acc[mi][ni], 0, 0, 0);
        }
        __syncthreads();
    }
    float* shf = smemf;
    float* sW  = smemf + 8448;
    for (int j = tid; j < 128*18; j += 256) {
        int c = j / 18, o = j - c*18;
        sW[c*20 + o] = (o < 6) ? w_cls[(size_t)(n0 + c)*6 + o]
                               : w_dlt[(size_t)(n0 + c)*12 + (o - 6)];
    }
    float bsh[4];
    #pragma unroll
    for (int ni = 0; ni < 4; ni++) bsh[ni] = b_sh[n0 + wc*64 + ni*16 + l15];
    float a18[18];
    #pragma unroll
    for (int o = 0; o < 18; o++) a18[o] = 0.f;
    const int rr = tid & 127, chalf = tid >> 7;
    #pragma unroll
    for (int pass = 0; pass < 2; pass++) {
        if (wc == pass) {
            #pragma unroll
            for (int mi = 0; mi < 4; mi++)
                #pragma unroll
                for (int ni = 0; ni < 4; ni++) {
                    int colL = ni*16 + l15;
                    int row0 = wr*64 + mi*16 + l4*4;
                    f32x4 v = acc[mi][ni];
                    f32x4 sv;
                    #pragma unroll
                    for (int r = 0; r < 4; r++) sv[r] = fmaxf(v[r] + bsh[ni], 0.f);
                    *(f32x4*)(shf + colL*132 + row0) = sv;
                }
        }
        __syncthreads();
        #pragma unroll 4
        for (int i = 0; i < 32; i++) {
            int c = chalf*32 + i;
            float v = shf[c*132 + rr];
            const float* wrow = sW + (pass*64 + c)*20;
            #pragma unroll
            for (int o = 0; o < 18; o++) a18[o] += v * wrow[o];
        }
        __syncthreads();
    }
    const int pixel = mtile*128 + rr;
    float* lo = out + (size_t)pixel*6;
    float* dl = out + DELTA_BASE + (size_t)pixel*12;
    #pragma unroll
    for (int o = 0; o < 6; o++)  atomicAdd(lo + o, a18[o]);
    #pragma unroll
    for (int o = 0; o < 12; o++) atomicAdd(dl + o, a18[6 + o]);
}

__global__ __launch_bounds__(256) void k_finalize(float* __restrict__ out,
                                                  const float* __restrict__ b_cls,
                                                  const float* __restrict__ b_dlt) {
    int pix = blockIdx.x*256 + threadIdx.x;
    if (pix >= NPIX) return;
    float* lo = out + (size_t)pix*6;
    float* pr = out + (size_t)LOGITS_N + (size_t)pix*6;
    float* dl = out + (size_t)DELTA_BASE + (size_t)pix*12;
    #pragma unroll
    for (int a = 0; a < 3; a++) {
        float l0 = lo[a*2]   + b_cls[a*2];
        float l1 = lo[a*2+1] + b_cls[a*2+1];
        lo[a*2] = l0; lo[a*2+1] = l1;
        float m = fmaxf(l0, l1);
        float e0 = __expf(l0 - m), e1 = __expf(l1 - m);
        float inv = 1.f / (e0 + e1);
        pr[a*2] = e0*inv; pr[a*2+1] = e1*inv;
    }
    #pragma unroll
    for (int o = 0; o < 12; o++) dl[o] += b_dlt[o];
}

extern "C" void kernel_launch(void* const* d_in, const int* in_sizes, int n_in,
                              void* d_out, int out_size, void* d_ws, size_t ws_size,
                              hipStream_t stream) {
    const float* in    = (const float*)d_in[0];
    const float* w_sh  = (const float*)d_in[1];
    const float* b_sh  = (const float*)d_in[2];
    const float* w_cls = (const float*)d_in[3];
    const float* b_cls = (const float*)d_in[4];
    const float* w_dlt = (const float*)d_in[5];
    const float* b_dlt = (const float*)d_in[6];
    float* out = (float*)d_out;

    const size_t in_p_elems = (size_t)BATCH*HP*HP*CIN;   // 17,305,600
    const size_t wt_elems   = (size_t)9*CO*CIN;          // 1,179,648
    const size_t part_elems = (size_t)2*NPIX*18;         // 2,359,296
    const size_t need = (in_p_elems + wt_elems)*2 + part_elems*4;  // ~46.4 MB

    if (ws_size >= need) {
        unsigned short* in_p = (unsigned short*)d_ws;
        unsigned short* wt   = in_p + in_p_elems;
        float* part = (float*)(wt + wt_elems);
        hipFuncSetAttribute((const void*)k_main8,
                            hipFuncAttributeMaxDynamicSharedMemorySize, 163840);
        int padq = (int)(((size_t)BATCH*HP*HP*64 + 255)/256);
        k_pad_convert<<<padq, 256, 0, stream>>>(in, in_p);
        k_wt_convert<<<9*CO, 256, 0, stream>>>(w_sh, wt);
        k_main8<<<512, 512, 163840, stream>>>(in_p, wt, b_sh, w_cls, w_dlt, part);
        k_finalize_ws<<<(NPIX + 255)/256, 256, 0, stream>>>(part, out, b_cls, b_dlt);
    } else {
        hipMemsetAsync(d_out, 0, (size_t)out_size * sizeof(float), stream);
        k_main_fb<<<2048, 256, 0, stream>>>(in, w_sh, b_sh, w_cls, w_dlt, out);
        k_finalize<<<(NPIX + 255)/256, 256, 0, stream>>>(out, b_cls, b_dlt);
    }
}